// Round 4
// baseline (622.830 us; speedup 1.0000x reference)
//
#include <hip/hip_runtime.h>

#define NCH 128   // EMBED
#define NH  8     // HEADS
#define HID 512
#define SLOPE 0.2f
#define BN_EPS 1e-5f
#define LDP 136   // padded LDS inner dim (bf16 units)

typedef __attribute__((ext_vector_type(8))) short short8;     // 8 bf16 (4 VGPRs)
typedef __attribute__((ext_vector_type(4))) float floatx4;    // 4 fp32 acc

__device__ inline unsigned short f2bf(float f) {  // RNE f32 -> bf16 bits
  unsigned u = __float_as_uint(f);
  u += 0x7fffu + ((u >> 16) & 1u);
  return (unsigned short)(u >> 16);
}
__device__ inline float bflo(unsigned u) { return __uint_as_float(u << 16); }
__device__ inline float bfhi(unsigned u) { return __uint_as_float(u & 0xffff0000u); }

// ---------------- zero fill ----------------
__global__ void fill_zero4(float* __restrict__ p, int n4) {
  int i = blockIdx.x * blockDim.x + threadIdx.x;
  if (i < n4) ((float4*)p)[i] = make_float4(0.f, 0.f, 0.f, 0.f);
}

// ---------------- weight transposes to bf16 ----------------
__global__ void prep_wbt(const float* __restrict__ W, unsigned short* __restrict__ WT) {
  // W [128][128] -> WT [n][k] bf16
  int i = blockIdx.x * 256 + threadIdx.x;   // 16384
  int n = i >> 7, k = i & 127;
  WT[i] = f2bf(W[k * NCH + n]);
}
__global__ void prep_w1t(const float* __restrict__ W1, unsigned short* __restrict__ W1T) {
  int i = blockIdx.x * 256 + threadIdx.x;   // 65536
  int j = i >> 7, k = i & 127;
  W1T[i] = f2bf(W1[k * HID + j]);
}
__global__ void prep_w2t(const float* __restrict__ W2, unsigned short* __restrict__ W2T) {
  int i = blockIdx.x * 256 + threadIdx.x;   // 65536
  int n = i >> 9, k = i & 511;
  W2T[i] = f2bf(W2[k * NCH + n]);
}

// ---------------- featb = bf16( x @ W ) via MFMA ----------------
__global__ __launch_bounds__(256) void feat_mfma(const float* __restrict__ x,
                                                 const unsigned short* __restrict__ WT,  // [128][128] WT[n][k]
                                                 unsigned short* __restrict__ featb, int N) {
  __shared__ unsigned short rowX[64 * LDP];   // 17.4 KB (reused for output assembly)
  __shared__ unsigned short wt[128 * LDP];    // 34.8 KB
  int tid = threadIdx.x;
  int r0 = blockIdx.x * 64;
  int lane = tid & 63, wid = tid >> 6;
  int quad = lane >> 4, lc = lane & 15;
  int mrow = (wid & 1) * 32;
  int chalf = (wid >> 1) * 64;

  // stage WT
  {
    int n = tid >> 1, kg = (tid & 1) * 64;
    const uint4* g = (const uint4*)(WT + n * NCH + kg);
    uint4* l = (uint4*)&wt[n * LDP + kg];
    for (int i = 0; i < 8; i++) l[i] = g[i];
  }
  // stage x rows as bf16
  {
    int r = tid >> 2, kg = (tid & 3) * 32;
    int gr = r0 + r;
    unsigned short tmp[32];
    if (gr < N) {
      const float4* gp = (const float4*)(x + (size_t)gr * NCH + kg);
      for (int i = 0; i < 8; i++) {
        float4 v = gp[i];
        tmp[i * 4 + 0] = f2bf(v.x); tmp[i * 4 + 1] = f2bf(v.y);
        tmp[i * 4 + 2] = f2bf(v.z); tmp[i * 4 + 3] = f2bf(v.w);
      }
    } else {
      for (int i = 0; i < 32; i++) tmp[i] = 0;
    }
    uint4* l = (uint4*)&rowX[r * LDP + kg];
    const uint4* s = (const uint4*)tmp;
    for (int i = 0; i < 4; i++) l[i] = s[i];
  }
  __syncthreads();

  floatx4 acc[2][4];
  for (int rt = 0; rt < 2; rt++) for (int tt = 0; tt < 4; tt++) acc[rt][tt] = (floatx4)(0.f);
  for (int kk = 0; kk < 4; kk++) {
    short8 a0 = *(const short8*)&rowX[(mrow + lc) * LDP + kk * 32 + quad * 8];
    short8 a1 = *(const short8*)&rowX[(mrow + 16 + lc) * LDP + kk * 32 + quad * 8];
    for (int tt = 0; tt < 4; tt++) {
      short8 b = *(const short8*)&wt[(chalf + tt * 16 + lc) * LDP + kk * 32 + quad * 8];
      acc[0][tt] = __builtin_amdgcn_mfma_f32_16x16x32_bf16(a0, b, acc[0][tt], 0, 0, 0);
      acc[1][tt] = __builtin_amdgcn_mfma_f32_16x16x32_bf16(a1, b, acc[1][tt], 0, 0, 0);
    }
  }
  __syncthreads();   // done reading rowX; reuse as output tile
  for (int rt = 0; rt < 2; rt++)
    for (int tt = 0; tt < 4; tt++)
      for (int r = 0; r < 4; r++)
        rowX[(mrow + rt * 16 + quad * 4 + r) * LDP + chalf + tt * 16 + lc] = f2bf(acc[rt][tt][r]);
  __syncthreads();
  {
    int r = tid >> 2, kg = (tid & 3) * 32;
    int gr = r0 + r;
    if (gr < N) {
      uint4* gp = (uint4*)(featb + (size_t)gr * NCH + kg);
      const uint4* l = (const uint4*)&rowX[r * LDP + kg];
      for (int i = 0; i < 4; i++) gp[i] = l[i];
    }
  }
}

// ---------------- el/er from bf16 feat ----------------
__global__ void compute_elr_b(const unsigned short* __restrict__ featb,
                              const float* __restrict__ attn_l,
                              const float* __restrict__ attn_r,
                              float* __restrict__ el, float* __restrict__ er, int N) {
  __shared__ float al[128], ar[128];
  if (threadIdx.x < 128) { al[threadIdx.x] = attn_l[threadIdx.x]; ar[threadIdx.x] = attn_r[threadIdx.x]; }
  __syncthreads();
  int i = blockIdx.x * blockDim.x + threadIdx.x;
  if (i >= N * NH) return;
  int n = i >> 3, h = i & 7;
  const uint4* f = (const uint4*)(featb + (size_t)n * NCH + h * 16);
  uint4 v0 = f[0], v1 = f[1];
  unsigned tmp[8] = {v0.x, v0.y, v0.z, v0.w, v1.x, v1.y, v1.z, v1.w};
  float sl = 0.f, sr = 0.f;
  for (int q = 0; q < 8; q++) {
    unsigned u = tmp[q];
    float lo = bflo(u), hi = bfhi(u);
    int c = h * 16 + q * 2;
    sl += lo * al[c] + hi * al[c + 1];
    sr += lo * ar[c] + hi * ar[c + 1];
  }
  el[i] = sl; er[i] = sr;
}

// ---------------- counting sort of edges by dst ----------------
__global__ void edge_hist(const int* __restrict__ dst, int* __restrict__ cnt, int E) {
  int i = blockIdx.x * 256 + threadIdx.x;
  if (i < E) atomicAdd(&cnt[dst[i]], 1);
}

__global__ void scan_part(const int* __restrict__ cnt, int* __restrict__ off,
                          int* __restrict__ bsum, int N) {
  __shared__ int sh[256];
  int t = threadIdx.x, i = blockIdx.x * 256 + t;
  int v = (i < N) ? cnt[i] : 0;
  sh[t] = v; __syncthreads();
  for (int d = 1; d < 256; d <<= 1) {
    int u = (t >= d) ? sh[t - d] : 0;
    __syncthreads();
    sh[t] += u;
    __syncthreads();
  }
  if (i < N) off[i] = sh[t] - v;
  if (t == 255) bsum[blockIdx.x] = sh[255];
}

__global__ void scan_top(int* __restrict__ bsum, int nb) {   // nb <= 256, 1 block
  __shared__ int sh[256];
  int t = threadIdx.x;
  int v = (t < nb) ? bsum[t] : 0;
  sh[t] = v; __syncthreads();
  for (int d = 1; d < 256; d <<= 1) {
    int u = (t >= d) ? sh[t - d] : 0;
    __syncthreads();
    sh[t] += u;
    __syncthreads();
  }
  if (t < nb) bsum[t] = sh[t] - v;
}

__global__ void scan_add(int* __restrict__ off, const int* __restrict__ bsum,
                         int* __restrict__ cursor, int N) {
  int i = blockIdx.x * 256 + threadIdx.x;
  if (i < N) {
    int v = off[i] + bsum[blockIdx.x];
    off[i] = v;
    cursor[i] = v;
  }
}

__global__ void edge_scatter(const int* __restrict__ src, const int* __restrict__ dst,
                             int* __restrict__ cursor, int* __restrict__ ssrc, int E) {
  int i = blockIdx.x * 256 + threadIdx.x;
  if (i < E) {
    int p = atomicAdd(&cursor[dst[i]], 1);
    ssrc[p] = src[i];
  }
}

// ---------------- gather + skip + bias + BN1 stats (1 wave / node) ----------------
// hbuf[d] = x[d] + gatbias + (sum_e w_e * featb[s]) / (sum_e w_e);  w_e = exp(leaky(el[s]+er[d]))
__global__ __launch_bounds__(256) void gat_gather2(const int* __restrict__ ssrc,
                                                   const int* __restrict__ off,
                                                   const int* __restrict__ cnt,
                                                   const float* __restrict__ el,
                                                   const float* __restrict__ er,
                                                   const unsigned short* __restrict__ featb,
                                                   const float* __restrict__ x,
                                                   const float* __restrict__ gatb,
                                                   float* __restrict__ hbuf,
                                                   float* __restrict__ stats, int N) {
  __shared__ float csum[128], csq[128];
  int tid = threadIdx.x;
  if (tid < 128) { csum[tid] = 0.f; csq[tid] = 0.f; }
  __syncthreads();
  int node = (blockIdx.x * 256 + tid) >> 6;
  int lane = tid & 63;
  int hh = lane & 7;          // head this lane computes exp for
  int hme = lane >> 3;        // head of this lane's channel pair (2*lane, 2*lane+1)
  float acc0 = 0.f, acc1 = 0.f, den = 0.f;
  if (node < N) {
    float erh = er[node * NH + hh];
    int beg = off[node], num = cnt[node];
    int i = 0;
    for (; i + 4 <= num; i += 4) {
      int s0 = ssrc[beg + i + 0], s1 = ssrc[beg + i + 1];
      int s2 = ssrc[beg + i + 2], s3 = ssrc[beg + i + 3];
      unsigned f0 = *(const unsigned*)(featb + (size_t)s0 * NCH + 2 * lane);
      unsigned f1 = *(const unsigned*)(featb + (size_t)s1 * NCH + 2 * lane);
      unsigned f2 = *(const unsigned*)(featb + (size_t)s2 * NCH + 2 * lane);
      unsigned f3 = *(const unsigned*)(featb + (size_t)s3 * NCH + 2 * lane);
      float e0 = el[s0 * NH + hh] + erh, e1 = el[s1 * NH + hh] + erh;
      float e2 = el[s2 * NH + hh] + erh, e3 = el[s3 * NH + hh] + erh;
      e0 = e0 > 0.f ? e0 : SLOPE * e0;  e1 = e1 > 0.f ? e1 : SLOPE * e1;
      e2 = e2 > 0.f ? e2 : SLOPE * e2;  e3 = e3 > 0.f ? e3 : SLOPE * e3;
      float w0 = __expf(e0), w1 = __expf(e1), w2 = __expf(e2), w3 = __expf(e3);
      float a0 = __shfl(w0, hme), a1 = __shfl(w1, hme);
      float a2 = __shfl(w2, hme), a3 = __shfl(w3, hme);
      acc0 += a0 * bflo(f0) + a1 * bflo(f1) + a2 * bflo(f2) + a3 * bflo(f3);
      acc1 += a0 * bfhi(f0) + a1 * bfhi(f1) + a2 * bfhi(f2) + a3 * bfhi(f3);
      den  += a0 + a1 + a2 + a3;
    }
    for (; i < num; i++) {
      int s = ssrc[beg + i];
      unsigned f = *(const unsigned*)(featb + (size_t)s * NCH + 2 * lane);
      float e = el[s * NH + hh] + erh;
      e = e > 0.f ? e : SLOPE * e;
      float w = __expf(e);
      float a = __shfl(w, hme);
      acc0 += a * bflo(f); acc1 += a * bfhi(f); den += a;
    }
    float inv = den > 0.f ? 1.f / den : 0.f;
    int c0 = 2 * lane;
    float2 xv = *(const float2*)(x + (size_t)node * NCH + c0);
    float h0 = xv.x + acc0 * inv + gatb[c0];
    float h1 = xv.y + acc1 * inv + gatb[c0 + 1];
    *(float2*)(hbuf + (size_t)node * NCH + c0) = make_float2(h0, h1);
    atomicAdd(&csum[c0], h0); atomicAdd(&csum[c0 + 1], h1);
    atomicAdd(&csq[c0], h0 * h0); atomicAdd(&csq[c0 + 1], h1 * h1);
  }
  __syncthreads();
  if (tid < 128) {
    atomicAdd(&stats[tid * 16], csum[tid]);
    atomicAdd(&stats[2048 + tid * 16], csq[tid]);
  }
}

// ---------------- finalize mean/rstd ----------------
__global__ void stats_finalize(const float* __restrict__ stats, float* __restrict__ mu,
                               float* __restrict__ rs, int n, int so) {
  int c = threadIdx.x;
  if (c < 128) {
    float s = stats[so + c * 16], sq = stats[so + 2048 + c * 16];
    float m = s / (float)n;
    float v = sq / (float)n - m * m;
    mu[c] = m;
    rs[c] = rsqrtf(v + BN_EPS);
  }
}

// ---------------- fused BN1 + FFN via bf16 MFMA + BN2 stats ----------------
// rowA = bf16(BN1(hbuf)); t = rowA + relu(rowA@W1+b1)@W2 + b2
__global__ __launch_bounds__(512) void ffn_mfma(const float* __restrict__ hbuf,
                                                const float* __restrict__ mu1, const float* __restrict__ rs1,
                                                const float* __restrict__ g1, const float* __restrict__ be1,
                                                const unsigned short* __restrict__ W1T,  // [512][128] bf16
                                                const unsigned short* __restrict__ W2T,  // [128][512] bf16
                                                const float* __restrict__ b1, const float* __restrict__ b2,
                                                float* __restrict__ t, float* __restrict__ stats, int N) {
  __shared__ unsigned short rowA[64 * LDP];
  __shared__ unsigned short w1t[128 * LDP];
  __shared__ unsigned short w2t[128 * LDP];
  __shared__ unsigned short hidL[64 * LDP];
  __shared__ float pscale[128], pshift[128];
  __shared__ float csum[128], csq[128];
  int tid = threadIdx.x;
  int r0 = blockIdx.x * 64;
  int lane = tid & 63, wid = tid >> 6;
  int quad = lane >> 4, lc = lane & 15;
  int mrow = (wid & 3) * 16;
  int chalf = (wid >> 2) * 64;

  if (tid < 128) {
    float s = g1[tid] * rs1[tid];
    pscale[tid] = s;
    pshift[tid] = be1[tid] - s * mu1[tid];
    csum[tid] = 0.f; csq[tid] = 0.f;
  }
  __syncthreads();

  // stage rowA = bf16(BN1(hbuf)): thread r = tid>>3, 16 channels at kg
  {
    int r = tid >> 3, kg = (tid & 7) * 16;
    int gr = r0 + r;
    unsigned short tmp[16];
    if (gr < N) {
      const float4* gp = (const float4*)(hbuf + (size_t)gr * NCH + kg);
      for (int i = 0; i < 4; i++) {
        float4 v = gp[i];
        int c = kg + i * 4;
        tmp[i * 4 + 0] = f2bf(v.x * pscale[c + 0] + pshift[c + 0]);
        tmp[i * 4 + 1] = f2bf(v.y * pscale[c + 1] + pshift[c + 1]);
        tmp[i * 4 + 2] = f2bf(v.z * pscale[c + 2] + pshift[c + 2]);
        tmp[i * 4 + 3] = f2bf(v.w * pscale[c + 3] + pshift[c + 3]);
      }
    } else {
      for (int i = 0; i < 16; i++) tmp[i] = 0;
    }
    uint4* l = (uint4*)&rowA[r * LDP + kg];
    const uint4* s = (const uint4*)tmp;
    l[0] = s[0]; l[1] = s[1];
  }

  floatx4 acc[4];
  for (int tt = 0; tt < 4; tt++) acc[tt] = (floatx4)(0.f);

  for (int ch = 0; ch < 4; ch++) {
    __syncthreads();
    {
      int n = tid >> 2, kg = (tid & 3) * 32;
      const uint4* gg1 = (const uint4*)(W1T + ((size_t)(ch * 128 + n)) * 128 + kg);
      const uint4* gg2 = (const uint4*)(W2T + (size_t)n * HID + ch * 128 + kg);
      uint4* l1 = (uint4*)&w1t[n * LDP + kg];
      uint4* l2 = (uint4*)&w2t[n * LDP + kg];
      for (int i = 0; i < 4; i++) l1[i] = gg1[i];
      for (int i = 0; i < 4; i++) l2[i] = gg2[i];
    }
    __syncthreads();

    floatx4 hacc[4];
    for (int tt = 0; tt < 4; tt++) hacc[tt] = (floatx4)(0.f);
    for (int kk = 0; kk < 4; kk++) {
      short8 a = *(const short8*)&rowA[(mrow + lc) * LDP + kk * 32 + quad * 8];
      for (int tt = 0; tt < 4; tt++) {
        short8 b = *(const short8*)&w1t[(chalf + tt * 16 + lc) * LDP + kk * 32 + quad * 8];
        hacc[tt] = __builtin_amdgcn_mfma_f32_16x16x32_bf16(a, b, hacc[tt], 0, 0, 0);
      }
    }
    for (int tt = 0; tt < 4; tt++) {
      float bv = b1[ch * 128 + chalf + tt * 16 + lc];
      for (int r = 0; r < 4; r++) {
        float v = hacc[tt][r] + bv;
        v = fmaxf(v, 0.f);
        hidL[(mrow + quad * 4 + r) * LDP + chalf + tt * 16 + lc] = f2bf(v);
      }
    }
    __syncthreads();

    for (int kk = 0; kk < 4; kk++) {
      short8 a = *(const short8*)&hidL[(mrow + lc) * LDP + kk * 32 + quad * 8];
      for (int tt = 0; tt < 4; tt++) {
        short8 b = *(const short8*)&w2t[(chalf + tt * 16 + lc) * LDP + kk * 32 + quad * 8];
        acc[tt] = __builtin_amdgcn_mfma_f32_16x16x32_bf16(a, b, acc[tt], 0, 0, 0);
      }
    }
  }

  // epilogue: t = base(bf16 rowA) + y + b2, BN2 stats
  for (int tt = 0; tt < 4; tt++) {
    int col = chalf + tt * 16 + lc;
    float b2v = b2[col];
    float s = 0.f, q = 0.f;
    for (int r = 0; r < 4; r++) {
      int grow = r0 + mrow + quad * 4 + r;
      if (grow < N) {
        unsigned short bu = rowA[(mrow + quad * 4 + r) * LDP + col];
        float base = __uint_as_float(((unsigned)bu) << 16);
        float tv = base + acc[tt][r] + b2v;
        t[(size_t)grow * NCH + col] = tv;
        s += tv; q += tv * tv;
      }
    }
    s += __shfl_xor(s, 16); s += __shfl_xor(s, 32);
    q += __shfl_xor(q, 16); q += __shfl_xor(q, 32);
    if (quad == 0) { atomicAdd(&csum[col], s); atomicAdd(&csq[col], q); }
  }
  __syncthreads();
  if (tid < 128) {
    atomicAdd(&stats[4096 + tid * 16], csum[tid]);
    atomicAdd(&stats[6144 + tid * 16], csq[tid]);
  }
}

// ---------------- BN2 apply -> out ----------------
__global__ void bn2_apply(const float* __restrict__ t,
                          const float* __restrict__ g, const float* __restrict__ b,
                          const float* __restrict__ mu, const float* __restrict__ rs,
                          float* __restrict__ out, int total) {
  int i = blockIdx.x * blockDim.x + threadIdx.x;
  if (i >= total) return;
  int c = i & 127;
  out[i] = g[c] * (t[i] - mu[c]) * rs[c] + b[c];
}

extern "C" void kernel_launch(void* const* d_in, const int* in_sizes, int n_in,
                              void* d_out, int out_size, void* d_ws, size_t ws_size,
                              hipStream_t stream) {
  const float* x       = (const float*)d_in[0];
  const int*   src     = (const int*)d_in[1];
  const int*   dst     = (const int*)d_in[2];
  const float* W       = (const float*)d_in[3];
  const float* attn_l  = (const float*)d_in[4];
  const float* attn_r  = (const float*)d_in[5];
  const float* gatb    = (const float*)d_in[6];
  const float* gamma1  = (const float*)d_in[7];
  const float* beta1   = (const float*)d_in[8];
  const float* gamma2  = (const float*)d_in[9];
  const float* beta2   = (const float*)d_in[10];
  const float* W1      = (const float*)d_in[11];
  const float* b1      = (const float*)d_in[12];
  const float* W2      = (const float*)d_in[13];
  const float* b2      = (const float*)d_in[14];
  float* out = (float*)d_out;

  const int N = in_sizes[0] / NCH;   // 50000
  const int E = in_sizes[1];         // 800000
  const int nb = (N + 255) / 256;    // scan blocks

  float* hbuf  = (float*)d_ws;             // N*128 f32 (pre-BN1 h)
  float* t     = hbuf + (size_t)N * NCH;   // N*128 f32 (pre-BN2 t)
  float* el    = t + (size_t)N * NCH;      // N*8
  float* er    = el + (size_t)N * NH;      // N*8
  float* stats = er + (size_t)N * NH;      // 8192
  float* mus   = stats + 4 * 2048;         // mu1, rs1, mu2, rs2 (128 each)
  unsigned short* featb = (unsigned short*)(mus + 512);  // N*128 bf16
  unsigned short* WT    = featb + (size_t)N * NCH;       // 128*128 bf16
  unsigned short* W1T   = WT + NCH * NCH;                // 512*128 bf16
  unsigned short* W2T   = W1T + HID * NCH;               // 128*512 bf16
  int* cnt    = (int*)(W2T + HID * NCH);                 // N
  int* off    = cnt + N;                                 // N
  int* cursor = off + N;                                 // N
  int* bsum   = cursor + N;                              // 256
  int* ssrc   = bsum + 256;                              // E

  fill_zero4<<<(2048 + 255) / 256, 256, 0, stream>>>(stats, 2048);
  fill_zero4<<<(N / 4 + 255) / 256, 256, 0, stream>>>((float*)cnt, N / 4);

  prep_wbt<<<NCH * NCH / 256, 256, 0, stream>>>(W, WT);
  prep_w1t<<<HID * NCH / 256, 256, 0, stream>>>(W1, W1T);
  prep_w2t<<<HID * NCH / 256, 256, 0, stream>>>(W2, W2T);

  feat_mfma<<<(N + 63) / 64, 256, 0, stream>>>(x, WT, featb, N);
  compute_elr_b<<<(N * NH + 255) / 256, 256, 0, stream>>>(featb, attn_l, attn_r, el, er, N);

  edge_hist<<<(E + 255) / 256, 256, 0, stream>>>(dst, cnt, E);
  scan_part<<<nb, 256, 0, stream>>>(cnt, off, bsum, N);
  scan_top<<<1, 256, 0, stream>>>(bsum, nb);
  scan_add<<<nb, 256, 0, stream>>>(off, bsum, cursor, N);
  edge_scatter<<<(E + 255) / 256, 256, 0, stream>>>(src, dst, cursor, ssrc, E);

  gat_gather2<<<(N * 64 + 255) / 256, 256, 0, stream>>>(ssrc, off, cnt, el, er, featb,
                                                        x, gatb, hbuf, stats, N);
  stats_finalize<<<1, 128, 0, stream>>>(stats, mus, mus + 128, N, 0);

  ffn_mfma<<<(N + 63) / 64, 512, 0, stream>>>(hbuf, mus, mus + 128, gamma1, beta1,
                                              W1T, W2T, b1, b2, t, stats, N);
  stats_finalize<<<1, 128, 0, stream>>>(stats, mus + 256, mus + 384, N, 4096);

  bn2_apply<<<(N * NCH + 255) / 256, 256, 0, stream>>>(t, gamma2, beta2,
                                                       mus + 256, mus + 384, out, N * NCH);
}

// Round 5
// 380.065 us; speedup vs baseline: 1.6387x; 1.6387x over previous
//
#include <hip/hip_runtime.h>

#define NCH 128   // EMBED
#define NH  8     // HEADS
#define HID 512
#define SLOPE 0.2f
#define BN_EPS 1e-5f
#define LDP 136   // padded LDS inner dim (bf16 units)
#define NPW 8     // nodes per wave in gather

typedef __attribute__((ext_vector_type(8))) short short8;     // 8 bf16 (4 VGPRs)
typedef __attribute__((ext_vector_type(4))) float floatx4;    // 4 fp32 acc

__device__ inline unsigned short f2bf(float f) {  // RNE f32 -> bf16 bits
  unsigned u = __float_as_uint(f);
  u += 0x7fffu + ((u >> 16) & 1u);
  return (unsigned short)(u >> 16);
}
__device__ inline float bflo(unsigned u) { return __uint_as_float(u << 16); }
__device__ inline float bfhi(unsigned u) { return __uint_as_float(u & 0xffff0000u); }

// ---------------- zero fill ----------------
__global__ void fill_zero4(float* __restrict__ p, int n4) {
  int i = blockIdx.x * blockDim.x + threadIdx.x;
  if (i < n4) ((float4*)p)[i] = make_float4(0.f, 0.f, 0.f, 0.f);
}

// ---------------- weight transposes to bf16 ----------------
__global__ void prep_wbt(const float* __restrict__ W, unsigned short* __restrict__ WT) {
  int i = blockIdx.x * 256 + threadIdx.x;   // 16384
  int n = i >> 7, k = i & 127;
  WT[i] = f2bf(W[k * NCH + n]);
}
__global__ void prep_w1t(const float* __restrict__ W1, unsigned short* __restrict__ W1T) {
  int i = blockIdx.x * 256 + threadIdx.x;   // 65536
  int j = i >> 7, k = i & 127;
  W1T[i] = f2bf(W1[k * HID + j]);
}
__global__ void prep_w2t(const float* __restrict__ W2, unsigned short* __restrict__ W2T) {
  int i = blockIdx.x * 256 + threadIdx.x;   // 65536
  int n = i >> 9, k = i & 511;
  W2T[i] = f2bf(W2[k * NCH + n]);
}

// ---------------- featb = bf16( x @ W ) via MFMA ----------------
__global__ __launch_bounds__(256) void feat_mfma(const float* __restrict__ x,
                                                 const unsigned short* __restrict__ WT,  // WT[n][k]
                                                 unsigned short* __restrict__ featb, int N) {
  __shared__ unsigned short rowX[64 * LDP];
  __shared__ unsigned short wt[128 * LDP];
  int tid = threadIdx.x;
  int r0 = blockIdx.x * 64;
  int lane = tid & 63, wid = tid >> 6;
  int quad = lane >> 4, lc = lane & 15;
  int mrow = (wid & 1) * 32;
  int chalf = (wid >> 1) * 64;

  {
    int n = tid >> 1, kg = (tid & 1) * 64;
    const uint4* g = (const uint4*)(WT + n * NCH + kg);
    uint4* l = (uint4*)&wt[n * LDP + kg];
    for (int i = 0; i < 8; i++) l[i] = g[i];
  }
  {
    int r = tid >> 2, kg = (tid & 3) * 32;
    int gr = r0 + r;
    unsigned short tmp[32];
    if (gr < N) {
      const float4* gp = (const float4*)(x + (size_t)gr * NCH + kg);
      for (int i = 0; i < 8; i++) {
        float4 v = gp[i];
        tmp[i * 4 + 0] = f2bf(v.x); tmp[i * 4 + 1] = f2bf(v.y);
        tmp[i * 4 + 2] = f2bf(v.z); tmp[i * 4 + 3] = f2bf(v.w);
      }
    } else {
      for (int i = 0; i < 32; i++) tmp[i] = 0;
    }
    uint4* l = (uint4*)&rowX[r * LDP + kg];
    const uint4* s = (const uint4*)tmp;
    for (int i = 0; i < 4; i++) l[i] = s[i];
  }
  __syncthreads();

  floatx4 acc[2][4];
  for (int rt = 0; rt < 2; rt++) for (int tt = 0; tt < 4; tt++) acc[rt][tt] = (floatx4)(0.f);
  for (int kk = 0; kk < 4; kk++) {
    short8 a0 = *(const short8*)&rowX[(mrow + lc) * LDP + kk * 32 + quad * 8];
    short8 a1 = *(const short8*)&rowX[(mrow + 16 + lc) * LDP + kk * 32 + quad * 8];
    for (int tt = 0; tt < 4; tt++) {
      short8 b = *(const short8*)&wt[(chalf + tt * 16 + lc) * LDP + kk * 32 + quad * 8];
      acc[0][tt] = __builtin_amdgcn_mfma_f32_16x16x32_bf16(a0, b, acc[0][tt], 0, 0, 0);
      acc[1][tt] = __builtin_amdgcn_mfma_f32_16x16x32_bf16(a1, b, acc[1][tt], 0, 0, 0);
    }
  }
  __syncthreads();
  for (int rt = 0; rt < 2; rt++)
    for (int tt = 0; tt < 4; tt++)
      for (int r = 0; r < 4; r++)
        rowX[(mrow + rt * 16 + quad * 4 + r) * LDP + chalf + tt * 16 + lc] = f2bf(acc[rt][tt][r]);
  __syncthreads();
  {
    int r = tid >> 2, kg = (tid & 3) * 32;
    int gr = r0 + r;
    if (gr < N) {
      uint4* gp = (uint4*)(featb + (size_t)gr * NCH + kg);
      const uint4* l = (const uint4*)&rowX[r * LDP + kg];
      for (int i = 0; i < 4; i++) gp[i] = l[i];
    }
  }
}

// ---------------- el/er from bf16 feat ----------------
__global__ void compute_elr_b(const unsigned short* __restrict__ featb,
                              const float* __restrict__ attn_l,
                              const float* __restrict__ attn_r,
                              float* __restrict__ el, float* __restrict__ er, int N) {
  __shared__ float al[128], ar[128];
  if (threadIdx.x < 128) { al[threadIdx.x] = attn_l[threadIdx.x]; ar[threadIdx.x] = attn_r[threadIdx.x]; }
  __syncthreads();
  int i = blockIdx.x * blockDim.x + threadIdx.x;
  if (i >= N * NH) return;
  int n = i >> 3, h = i & 7;
  const uint4* f = (const uint4*)(featb + (size_t)n * NCH + h * 16);
  uint4 v0 = f[0], v1 = f[1];
  unsigned tmp[8] = {v0.x, v0.y, v0.z, v0.w, v1.x, v1.y, v1.z, v1.w};
  float sl = 0.f, sr = 0.f;
  for (int q = 0; q < 8; q++) {
    unsigned u = tmp[q];
    float lo = bflo(u), hi = bfhi(u);
    int c = h * 16 + q * 2;
    sl += lo * al[c] + hi * al[c + 1];
    sr += lo * ar[c] + hi * ar[c + 1];
  }
  el[i] = sl; er[i] = sr;
}

// ---------------- counting sort of edges by dst ----------------
__global__ void edge_hist(const int* __restrict__ dst, int* __restrict__ cnt, int E) {
  int i = blockIdx.x * 256 + threadIdx.x;
  if (i < E) atomicAdd(&cnt[dst[i]], 1);
}

__global__ void scan_part(const int* __restrict__ cnt, int* __restrict__ off,
                          int* __restrict__ bsum, int N) {
  __shared__ int sh[256];
  int t = threadIdx.x, i = blockIdx.x * 256 + t;
  int v = (i < N) ? cnt[i] : 0;
  sh[t] = v; __syncthreads();
  for (int d = 1; d < 256; d <<= 1) {
    int u = (t >= d) ? sh[t - d] : 0;
    __syncthreads();
    sh[t] += u;
    __syncthreads();
  }
  if (i < N) off[i] = sh[t] - v;
  if (t == 255) bsum[blockIdx.x] = sh[255];
}

__global__ void scan_top(int* __restrict__ bsum, int nb) {   // nb <= 256, 1 block
  __shared__ int sh[256];
  int t = threadIdx.x;
  int v = (t < nb) ? bsum[t] : 0;
  sh[t] = v; __syncthreads();
  for (int d = 1; d < 256; d <<= 1) {
    int u = (t >= d) ? sh[t - d] : 0;
    __syncthreads();
    sh[t] += u;
    __syncthreads();
  }
  if (t < nb) bsum[t] = sh[t] - v;
}

__global__ void scan_add(int* __restrict__ off, const int* __restrict__ bsum,
                         int* __restrict__ cursor, int N) {
  int i = blockIdx.x * 256 + threadIdx.x;
  if (i < N) {
    int v = off[i] + bsum[blockIdx.x];
    off[i] = v;
    cursor[i] = v;
  }
}

__global__ void edge_scatter(const int* __restrict__ src, const int* __restrict__ dst,
                             int* __restrict__ cursor, int* __restrict__ ssrc, int E) {
  int i = blockIdx.x * 256 + threadIdx.x;
  if (i < E) {
    int p = atomicAdd(&cursor[dst[i]], 1);
    ssrc[p] = src[i];
  }
}

// ---------------- gather + skip + bias + fused BN1 stats ----------------
// 4 waves/block, NPW nodes per wave (contiguous), per-lane register stats,
// LDS cross-wave reduce, ONE global atomic per channel per block.
__global__ __launch_bounds__(256) void gat_gather3(const int* __restrict__ ssrc,
                                                   const int* __restrict__ off,
                                                   const int* __restrict__ cnt,
                                                   const float* __restrict__ el,
                                                   const float* __restrict__ er,
                                                   const unsigned short* __restrict__ featb,
                                                   const float* __restrict__ x,
                                                   const float* __restrict__ gatb,
                                                   float* __restrict__ hbuf,
                                                   float* __restrict__ stats, int N) {
  __shared__ float ps[4][128], pq[4][128];
  int tid = threadIdx.x;
  int lane = tid & 63, w = tid >> 6;
  int hme = lane >> 3;         // head of this lane's channel pair
  int c0 = 2 * lane;
  float gb0 = gatb[c0], gb1 = gatb[c0 + 1];
  float s0 = 0.f, s1 = 0.f, q0 = 0.f, q1 = 0.f;
  int base = blockIdx.x * (4 * NPW) + w * NPW;
  for (int j = 0; j < NPW; j++) {
    int node = base + j;
    if (node >= N) break;
    node = __builtin_amdgcn_readfirstlane(node);
    float erh = er[node * NH + hme];
    int beg = off[node], num = cnt[node];
    float acc0 = 0.f, acc1 = 0.f, den = 0.f;
    int i = 0;
    for (; i + 4 <= num; i += 4) {
      int sa = ssrc[beg + i + 0], sb = ssrc[beg + i + 1];
      int sc = ssrc[beg + i + 2], sd = ssrc[beg + i + 3];
      unsigned f0 = *(const unsigned*)(featb + (size_t)sa * NCH + c0);
      unsigned f1 = *(const unsigned*)(featb + (size_t)sb * NCH + c0);
      unsigned f2 = *(const unsigned*)(featb + (size_t)sc * NCH + c0);
      unsigned f3 = *(const unsigned*)(featb + (size_t)sd * NCH + c0);
      float e0 = el[sa * NH + hme] + erh, e1 = el[sb * NH + hme] + erh;
      float e2 = el[sc * NH + hme] + erh, e3 = el[sd * NH + hme] + erh;
      e0 = e0 > 0.f ? e0 : SLOPE * e0;  e1 = e1 > 0.f ? e1 : SLOPE * e1;
      e2 = e2 > 0.f ? e2 : SLOPE * e2;  e3 = e3 > 0.f ? e3 : SLOPE * e3;
      float w0 = __expf(e0), w1 = __expf(e1), w2 = __expf(e2), w3 = __expf(e3);
      acc0 += w0 * bflo(f0) + w1 * bflo(f1) + w2 * bflo(f2) + w3 * bflo(f3);
      acc1 += w0 * bfhi(f0) + w1 * bfhi(f1) + w2 * bfhi(f2) + w3 * bfhi(f3);
      den  += w0 + w1 + w2 + w3;
    }
    for (; i < num; i++) {
      int s = ssrc[beg + i];
      unsigned f = *(const unsigned*)(featb + (size_t)s * NCH + c0);
      float e = el[s * NH + hme] + erh;
      e = e > 0.f ? e : SLOPE * e;
      float wv = __expf(e);
      acc0 += wv * bflo(f); acc1 += wv * bfhi(f); den += wv;
    }
    float inv = den > 0.f ? 1.f / den : 0.f;
    float2 xv = *(const float2*)(x + (size_t)node * NCH + c0);
    float h0 = xv.x + acc0 * inv + gb0;
    float h1 = xv.y + acc1 * inv + gb1;
    *(float2*)(hbuf + (size_t)node * NCH + c0) = make_float2(h0, h1);
    s0 += h0; s1 += h1; q0 += h0 * h0; q1 += h1 * h1;
  }
  ps[w][c0] = s0; ps[w][c0 + 1] = s1;
  pq[w][c0] = q0; pq[w][c0 + 1] = q1;
  __syncthreads();
  if (tid < 128) {
    float ss = ps[0][tid] + ps[1][tid] + ps[2][tid] + ps[3][tid];
    float qq = pq[0][tid] + pq[1][tid] + pq[2][tid] + pq[3][tid];
    atomicAdd(&stats[tid * 16], ss);
    atomicAdd(&stats[2048 + tid * 16], qq);
  }
}

// ---------------- finalize mean/rstd ----------------
__global__ void stats_finalize(const float* __restrict__ stats, float* __restrict__ mu,
                               float* __restrict__ rs, int n, int so) {
  int c = threadIdx.x;
  if (c < 128) {
    float s = stats[so + c * 16], sq = stats[so + 2048 + c * 16];
    float m = s / (float)n;
    float v = sq / (float)n - m * m;
    mu[c] = m;
    rs[c] = rsqrtf(v + BN_EPS);
  }
}

// ---------------- fused BN1 + FFN via bf16 MFMA + BN2 stats ----------------
__global__ __launch_bounds__(512) void ffn_mfma(const float* __restrict__ hbuf,
                                                const float* __restrict__ mu1, const float* __restrict__ rs1,
                                                const float* __restrict__ g1, const float* __restrict__ be1,
                                                const unsigned short* __restrict__ W1T,  // [512][128] bf16
                                                const unsigned short* __restrict__ W2T,  // [128][512] bf16
                                                const float* __restrict__ b1, const float* __restrict__ b2,
                                                float* __restrict__ t, float* __restrict__ stats, int N) {
  __shared__ unsigned short rowA[64 * LDP];
  __shared__ unsigned short w1t[128 * LDP];
  __shared__ unsigned short w2t[128 * LDP];
  __shared__ unsigned short hidL[64 * LDP];
  __shared__ float pscale[128], pshift[128];
  __shared__ float csum[128], csq[128];
  int tid = threadIdx.x;
  int r0 = blockIdx.x * 64;
  int lane = tid & 63, wid = tid >> 6;
  int quad = lane >> 4, lc = lane & 15;
  int mrow = (wid & 3) * 16;
  int chalf = (wid >> 2) * 64;

  if (tid < 128) {
    float s = g1[tid] * rs1[tid];
    pscale[tid] = s;
    pshift[tid] = be1[tid] - s * mu1[tid];
    csum[tid] = 0.f; csq[tid] = 0.f;
  }
  __syncthreads();

  {
    int r = tid >> 3, kg = (tid & 7) * 16;
    int gr = r0 + r;
    unsigned short tmp[16];
    if (gr < N) {
      const float4* gp = (const float4*)(hbuf + (size_t)gr * NCH + kg);
      for (int i = 0; i < 4; i++) {
        float4 v = gp[i];
        int c = kg + i * 4;
        tmp[i * 4 + 0] = f2bf(v.x * pscale[c + 0] + pshift[c + 0]);
        tmp[i * 4 + 1] = f2bf(v.y * pscale[c + 1] + pshift[c + 1]);
        tmp[i * 4 + 2] = f2bf(v.z * pscale[c + 2] + pshift[c + 2]);
        tmp[i * 4 + 3] = f2bf(v.w * pscale[c + 3] + pshift[c + 3]);
      }
    } else {
      for (int i = 0; i < 16; i++) tmp[i] = 0;
    }
    uint4* l = (uint4*)&rowA[r * LDP + kg];
    const uint4* s = (const uint4*)tmp;
    l[0] = s[0]; l[1] = s[1];
  }

  floatx4 acc[4];
  for (int tt = 0; tt < 4; tt++) acc[tt] = (floatx4)(0.f);

  for (int ch = 0; ch < 4; ch++) {
    __syncthreads();
    {
      int n = tid >> 2, kg = (tid & 3) * 32;
      const uint4* gg1 = (const uint4*)(W1T + ((size_t)(ch * 128 + n)) * 128 + kg);
      const uint4* gg2 = (const uint4*)(W2T + (size_t)n * HID + ch * 128 + kg);
      uint4* l1 = (uint4*)&w1t[n * LDP + kg];
      uint4* l2 = (uint4*)&w2t[n * LDP + kg];
      for (int i = 0; i < 4; i++) l1[i] = gg1[i];
      for (int i = 0; i < 4; i++) l2[i] = gg2[i];
    }
    __syncthreads();

    floatx4 hacc[4];
    for (int tt = 0; tt < 4; tt++) hacc[tt] = (floatx4)(0.f);
    for (int kk = 0; kk < 4; kk++) {
      short8 a = *(const short8*)&rowA[(mrow + lc) * LDP + kk * 32 + quad * 8];
      for (int tt = 0; tt < 4; tt++) {
        short8 b = *(const short8*)&w1t[(chalf + tt * 16 + lc) * LDP + kk * 32 + quad * 8];
        hacc[tt] = __builtin_amdgcn_mfma_f32_16x16x32_bf16(a, b, hacc[tt], 0, 0, 0);
      }
    }
    for (int tt = 0; tt < 4; tt++) {
      float bv = b1[ch * 128 + chalf + tt * 16 + lc];
      for (int r = 0; r < 4; r++) {
        float v = hacc[tt][r] + bv;
        v = fmaxf(v, 0.f);
        hidL[(mrow + quad * 4 + r) * LDP + chalf + tt * 16 + lc] = f2bf(v);
      }
    }
    __syncthreads();

    for (int kk = 0; kk < 4; kk++) {
      short8 a = *(const short8*)&hidL[(mrow + lc) * LDP + kk * 32 + quad * 8];
      for (int tt = 0; tt < 4; tt++) {
        short8 b = *(const short8*)&w2t[(chalf + tt * 16 + lc) * LDP + kk * 32 + quad * 8];
        acc[tt] = __builtin_amdgcn_mfma_f32_16x16x32_bf16(a, b, acc[tt], 0, 0, 0);
      }
    }
  }

  for (int tt = 0; tt < 4; tt++) {
    int col = chalf + tt * 16 + lc;
    float b2v = b2[col];
    float s = 0.f, q = 0.f;
    for (int r = 0; r < 4; r++) {
      int grow = r0 + mrow + quad * 4 + r;
      if (grow < N) {
        unsigned short bu = rowA[(mrow + quad * 4 + r) * LDP + col];
        float base = __uint_as_float(((unsigned)bu) << 16);
        float tv = base + acc[tt][r] + b2v;
        t[(size_t)grow * NCH + col] = tv;
        s += tv; q += tv * tv;
      }
    }
    s += __shfl_xor(s, 16); s += __shfl_xor(s, 32);
    q += __shfl_xor(q, 16); q += __shfl_xor(q, 32);
    if (quad == 0) { atomicAdd(&csum[col], s); atomicAdd(&csq[col], q); }
  }
  __syncthreads();
  if (tid < 128) {
    atomicAdd(&stats[4096 + tid * 16], csum[tid]);
    atomicAdd(&stats[6144 + tid * 16], csq[tid]);
  }
}

// ---------------- BN2 apply -> out ----------------
__global__ void bn2_apply(const float* __restrict__ t,
                          const float* __restrict__ g, const float* __restrict__ b,
                          const float* __restrict__ mu, const float* __restrict__ rs,
                          float* __restrict__ out, int total) {
  int i = blockIdx.x * blockDim.x + threadIdx.x;
  if (i >= total) return;
  int c = i & 127;
  out[i] = g[c] * (t[i] - mu[c]) * rs[c] + b[c];
}

extern "C" void kernel_launch(void* const* d_in, const int* in_sizes, int n_in,
                              void* d_out, int out_size, void* d_ws, size_t ws_size,
                              hipStream_t stream) {
  const float* x       = (const float*)d_in[0];
  const int*   src     = (const int*)d_in[1];
  const int*   dst     = (const int*)d_in[2];
  const float* W       = (const float*)d_in[3];
  const float* attn_l  = (const float*)d_in[4];
  const float* attn_r  = (const float*)d_in[5];
  const float* gatb    = (const float*)d_in[6];
  const float* gamma1  = (const float*)d_in[7];
  const float* beta1   = (const float*)d_in[8];
  const float* gamma2  = (const float*)d_in[9];
  const float* beta2   = (const float*)d_in[10];
  const float* W1      = (const float*)d_in[11];
  const float* b1      = (const float*)d_in[12];
  const float* W2      = (const float*)d_in[13];
  const float* b2      = (const float*)d_in[14];
  float* out = (float*)d_out;

  const int N = in_sizes[0] / NCH;   // 50000
  const int E = in_sizes[1];         // 800000
  const int nb = (N + 255) / 256;    // scan blocks

  float* hbuf  = (float*)d_ws;             // N*128 f32 (pre-BN1 h)
  float* t     = hbuf + (size_t)N * NCH;   // N*128 f32 (pre-BN2 t)
  float* el    = t + (size_t)N * NCH;      // N*8
  float* er    = el + (size_t)N * NH;      // N*8
  float* stats = er + (size_t)N * NH;      // 8192
  float* mus   = stats + 4 * 2048;         // mu1, rs1, mu2, rs2 (128 each)
  unsigned short* featb = (unsigned short*)(mus + 512);  // N*128 bf16
  unsigned short* WT    = featb + (size_t)N * NCH;       // 128*128 bf16
  unsigned short* W1T   = WT + NCH * NCH;                // 512*128 bf16
  unsigned short* W2T   = W1T + HID * NCH;               // 128*512 bf16
  int* cnt    = (int*)(W2T + HID * NCH);                 // N
  int* off    = cnt + N;                                 // N
  int* cursor = off + N;                                 // N
  int* bsum   = cursor + N;                              // 256
  int* ssrc   = bsum + 256;                              // E

  fill_zero4<<<(2048 + 255) / 256, 256, 0, stream>>>(stats, 2048);
  fill_zero4<<<(N / 4 + 255) / 256, 256, 0, stream>>>((float*)cnt, N / 4);

  prep_wbt<<<NCH * NCH / 256, 256, 0, stream>>>(W, WT);
  prep_w1t<<<HID * NCH / 256, 256, 0, stream>>>(W1, W1T);
  prep_w2t<<<HID * NCH / 256, 256, 0, stream>>>(W2, W2T);

  feat_mfma<<<(N + 63) / 64, 256, 0, stream>>>(x, WT, featb, N);
  compute_elr_b<<<(N * NH + 255) / 256, 256, 0, stream>>>(featb, attn_l, attn_r, el, er, N);

  edge_hist<<<(E + 255) / 256, 256, 0, stream>>>(dst, cnt, E);
  scan_part<<<nb, 256, 0, stream>>>(cnt, off, bsum, N);
  scan_top<<<1, 256, 0, stream>>>(bsum, nb);
  scan_add<<<nb, 256, 0, stream>>>(off, bsum, cursor, N);
  edge_scatter<<<(E + 255) / 256, 256, 0, stream>>>(src, dst, cursor, ssrc, E);

  gat_gather3<<<(N + 4 * NPW - 1) / (4 * NPW), 256, 0, stream>>>(ssrc, off, cnt, el, er, featb,
                                                                 x, gatb, hbuf, stats, N);
  stats_finalize<<<1, 128, 0, stream>>>(stats, mus, mus + 128, N, 0);

  ffn_mfma<<<(N + 63) / 64, 512, 0, stream>>>(hbuf, mus, mus + 128, gamma1, beta1,
                                              W1T, W2T, b1, b2, t, stats, N);
  stats_finalize<<<1, 128, 0, stream>>>(stats, mus + 256, mus + 384, N, 4096);

  bn2_apply<<<(N * NCH + 255) / 256, 256, 0, stream>>>(t, gamma2, beta2,
                                                       mus + 256, mus + 384, out, N * NCH);
}

// Round 6
// 344.244 us; speedup vs baseline: 1.8093x; 1.1041x over previous
//
#include <hip/hip_runtime.h>

#define NCH 128   // EMBED
#define NH  8     // HEADS
#define HID 512
#define SLOPE 0.2f
#define BN_EPS 1e-5f
#define LDP 136   // padded LDS inner dim (bf16 units) - used by feat_mfma only
#define NPW 8     // nodes per wave in gather

typedef __attribute__((ext_vector_type(8))) short short8;     // 8 bf16 (4 VGPRs)
typedef __attribute__((ext_vector_type(4))) float floatx4;    // 4 fp32 acc

__device__ inline unsigned short f2bf(float f) {  // RNE f32 -> bf16 bits
  unsigned u = __float_as_uint(f);
  u += 0x7fffu + ((u >> 16) & 1u);
  return (unsigned short)(u >> 16);
}
__device__ inline float bflo(unsigned u) { return __uint_as_float(u << 16); }
__device__ inline float bfhi(unsigned u) { return __uint_as_float(u & 0xffff0000u); }

// ---------------- zero fill ----------------
__global__ void fill_zero4(float* __restrict__ p, int n4) {
  int i = blockIdx.x * blockDim.x + threadIdx.x;
  if (i < n4) ((float4*)p)[i] = make_float4(0.f, 0.f, 0.f, 0.f);
}

// ---------------- weight prep ----------------
// feat GEMM weight: WT[n][k] bf16 (row-linear, staged padded in feat_mfma)
__global__ void prep_wbt(const float* __restrict__ W, unsigned short* __restrict__ WT) {
  int i = blockIdx.x * 256 + threadIdx.x;   // 16384
  int n = i >> 7, k = i & 127;
  WT[i] = f2bf(W[k * NCH + n]);
}
// FFN weights in FRAGMENT-CONTIGUOUS order:
// w1f: addr = (ntile*4 + kk)*512 + lane*8 + j ; lane=quad*16+lc
//      element = W1[k = kk*32 + quad*8 + j][n = ntile*16 + lc]   (ntile 0..31 over 512 hid)
__global__ void prep_w1f(const float* __restrict__ W1, unsigned short* __restrict__ w1f) {
  int i = blockIdx.x * 256 + threadIdx.x;   // 65536
  int ntile = i >> 11, kk = (i >> 9) & 3, lane = (i >> 3) & 63, j = i & 7;
  int k = kk * 32 + (lane >> 4) * 8 + j;
  int n = ntile * 16 + (lane & 15);
  w1f[i] = f2bf(W1[k * HID + n]);
}
// w2f: addr = ((ch*8 + nt)*4 + kk)*512 + lane*8 + j
//      element = W2[k = ch*128 + kk*32 + quad*8 + j][n = nt*16 + lc]
__global__ void prep_w2f(const float* __restrict__ W2, unsigned short* __restrict__ w2f) {
  int i = blockIdx.x * 256 + threadIdx.x;   // 65536
  int ch = i >> 14, nt = (i >> 11) & 7, kk = (i >> 9) & 3, lane = (i >> 3) & 63, j = i & 7;
  int k = ch * 128 + kk * 32 + (lane >> 4) * 8 + j;
  int n = nt * 16 + (lane & 15);
  w2f[i] = f2bf(W2[k * NCH + n]);
}

// ---------------- featb = bf16( x @ W ) via MFMA ----------------
__global__ __launch_bounds__(256) void feat_mfma(const float* __restrict__ x,
                                                 const unsigned short* __restrict__ WT,  // WT[n][k]
                                                 unsigned short* __restrict__ featb, int N) {
  __shared__ unsigned short rowX[64 * LDP];
  __shared__ unsigned short wt[128 * LDP];
  int tid = threadIdx.x;
  int r0 = blockIdx.x * 64;
  int lane = tid & 63, wid = tid >> 6;
  int quad = lane >> 4, lc = lane & 15;
  int mrow = (wid & 1) * 32;
  int chalf = (wid >> 1) * 64;

  {
    int n = tid >> 1, kg = (tid & 1) * 64;
    const uint4* g = (const uint4*)(WT + n * NCH + kg);
    uint4* l = (uint4*)&wt[n * LDP + kg];
    for (int i = 0; i < 8; i++) l[i] = g[i];
  }
  {
    int r = tid >> 2, kg = (tid & 3) * 32;
    int gr = r0 + r;
    unsigned short tmp[32];
    if (gr < N) {
      const float4* gp = (const float4*)(x + (size_t)gr * NCH + kg);
      for (int i = 0; i < 8; i++) {
        float4 v = gp[i];
        tmp[i * 4 + 0] = f2bf(v.x); tmp[i * 4 + 1] = f2bf(v.y);
        tmp[i * 4 + 2] = f2bf(v.z); tmp[i * 4 + 3] = f2bf(v.w);
      }
    } else {
      for (int i = 0; i < 32; i++) tmp[i] = 0;
    }
    uint4* l = (uint4*)&rowX[r * LDP + kg];
    const uint4* s = (const uint4*)tmp;
    for (int i = 0; i < 4; i++) l[i] = s[i];
  }
  __syncthreads();

  floatx4 acc[2][4];
  for (int rt = 0; rt < 2; rt++) for (int tt = 0; tt < 4; tt++) acc[rt][tt] = (floatx4)(0.f);
  for (int kk = 0; kk < 4; kk++) {
    short8 a0 = *(const short8*)&rowX[(mrow + lc) * LDP + kk * 32 + quad * 8];
    short8 a1 = *(const short8*)&rowX[(mrow + 16 + lc) * LDP + kk * 32 + quad * 8];
    for (int tt = 0; tt < 4; tt++) {
      short8 b = *(const short8*)&wt[(chalf + tt * 16 + lc) * LDP + kk * 32 + quad * 8];
      acc[0][tt] = __builtin_amdgcn_mfma_f32_16x16x32_bf16(a0, b, acc[0][tt], 0, 0, 0);
      acc[1][tt] = __builtin_amdgcn_mfma_f32_16x16x32_bf16(a1, b, acc[1][tt], 0, 0, 0);
    }
  }
  __syncthreads();
  for (int rt = 0; rt < 2; rt++)
    for (int tt = 0; tt < 4; tt++)
      for (int r = 0; r < 4; r++)
        rowX[(mrow + rt * 16 + quad * 4 + r) * LDP + chalf + tt * 16 + lc] = f2bf(acc[rt][tt][r]);
  __syncthreads();
  {
    int r = tid >> 2, kg = (tid & 3) * 32;
    int gr = r0 + r;
    if (gr < N) {
      uint4* gp = (uint4*)(featb + (size_t)gr * NCH + kg);
      const uint4* l = (const uint4*)&rowX[r * LDP + kg];
      for (int i = 0; i < 4; i++) gp[i] = l[i];
    }
  }
}

// ---------------- el/er from bf16 feat ----------------
__global__ void compute_elr_b(const unsigned short* __restrict__ featb,
                              const float* __restrict__ attn_l,
                              const float* __restrict__ attn_r,
                              float* __restrict__ el, float* __restrict__ er, int N) {
  __shared__ float al[128], ar[128];
  if (threadIdx.x < 128) { al[threadIdx.x] = attn_l[threadIdx.x]; ar[threadIdx.x] = attn_r[threadIdx.x]; }
  __syncthreads();
  int i = blockIdx.x * blockDim.x + threadIdx.x;
  if (i >= N * NH) return;
  int n = i >> 3, h = i & 7;
  const uint4* f = (const uint4*)(featb + (size_t)n * NCH + h * 16);
  uint4 v0 = f[0], v1 = f[1];
  unsigned tmp[8] = {v0.x, v0.y, v0.z, v0.w, v1.x, v1.y, v1.z, v1.w};
  float sl = 0.f, sr = 0.f;
  for (int q = 0; q < 8; q++) {
    unsigned u = tmp[q];
    float lo = bflo(u), hi = bfhi(u);
    int c = h * 16 + q * 2;
    sl += lo * al[c] + hi * al[c + 1];
    sr += lo * ar[c] + hi * ar[c + 1];
  }
  el[i] = sl; er[i] = sr;
}

// ---------------- counting sort of edges by dst ----------------
__global__ void edge_hist(const int* __restrict__ dst, int* __restrict__ cnt, int E) {
  int i = blockIdx.x * 256 + threadIdx.x;
  if (i < E) atomicAdd(&cnt[dst[i]], 1);
}

__global__ void scan_part(const int* __restrict__ cnt, int* __restrict__ off,
                          int* __restrict__ bsum, int N) {
  __shared__ int sh[256];
  int t = threadIdx.x, i = blockIdx.x * 256 + t;
  int v = (i < N) ? cnt[i] : 0;
  sh[t] = v; __syncthreads();
  for (int d = 1; d < 256; d <<= 1) {
    int u = (t >= d) ? sh[t - d] : 0;
    __syncthreads();
    sh[t] += u;
    __syncthreads();
  }
  if (i < N) off[i] = sh[t] - v;
  if (t == 255) bsum[blockIdx.x] = sh[255];
}

__global__ void scan_top(int* __restrict__ bsum, int nb) {   // nb <= 256, 1 block
  __shared__ int sh[256];
  int t = threadIdx.x;
  int v = (t < nb) ? bsum[t] : 0;
  sh[t] = v; __syncthreads();
  for (int d = 1; d < 256; d <<= 1) {
    int u = (t >= d) ? sh[t - d] : 0;
    __syncthreads();
    sh[t] += u;
    __syncthreads();
  }
  if (t < nb) bsum[t] = sh[t] - v;
}

__global__ void scan_add(int* __restrict__ off, const int* __restrict__ bsum,
                         int* __restrict__ cursor, int N) {
  int i = blockIdx.x * 256 + threadIdx.x;
  if (i < N) {
    int v = off[i] + bsum[blockIdx.x];
    off[i] = v;
    cursor[i] = v;
  }
}

__global__ void edge_scatter(const int* __restrict__ src, const int* __restrict__ dst,
                             int* __restrict__ cursor, int* __restrict__ ssrc, int E) {
  int i = blockIdx.x * 256 + threadIdx.x;
  if (i < E) {
    int p = atomicAdd(&cursor[dst[i]], 1);
    ssrc[p] = src[i];
  }
}

// ---------------- gather + skip + bias + fused BN1 stats ----------------
__global__ __launch_bounds__(256) void gat_gather3(const int* __restrict__ ssrc,
                                                   const int* __restrict__ off,
                                                   const int* __restrict__ cnt,
                                                   const float* __restrict__ el,
                                                   const float* __restrict__ er,
                                                   const unsigned short* __restrict__ featb,
                                                   const float* __restrict__ x,
                                                   const float* __restrict__ gatb,
                                                   float* __restrict__ hbuf,
                                                   float* __restrict__ stats, int N) {
  __shared__ float ps[4][128], pq[4][128];
  int tid = threadIdx.x;
  int lane = tid & 63, w = tid >> 6;
  int hme = lane >> 3;         // head of this lane's channel pair
  int c0 = 2 * lane;
  float gb0 = gatb[c0], gb1 = gatb[c0 + 1];
  float s0 = 0.f, s1 = 0.f, q0 = 0.f, q1 = 0.f;
  int base = blockIdx.x * (4 * NPW) + w * NPW;
  for (int j = 0; j < NPW; j++) {
    int node = base + j;
    if (node >= N) break;
    node = __builtin_amdgcn_readfirstlane(node);
    float erh = er[node * NH + hme];
    int beg = off[node], num = cnt[node];
    float acc0 = 0.f, acc1 = 0.f, den = 0.f;
    int i = 0;
    for (; i + 4 <= num; i += 4) {
      int sa = ssrc[beg + i + 0], sb = ssrc[beg + i + 1];
      int sc = ssrc[beg + i + 2], sd = ssrc[beg + i + 3];
      unsigned f0 = *(const unsigned*)(featb + (size_t)sa * NCH + c0);
      unsigned f1 = *(const unsigned*)(featb + (size_t)sb * NCH + c0);
      unsigned f2 = *(const unsigned*)(featb + (size_t)sc * NCH + c0);
      unsigned f3 = *(const unsigned*)(featb + (size_t)sd * NCH + c0);
      float e0 = el[sa * NH + hme] + erh, e1 = el[sb * NH + hme] + erh;
      float e2 = el[sc * NH + hme] + erh, e3 = el[sd * NH + hme] + erh;
      e0 = e0 > 0.f ? e0 : SLOPE * e0;  e1 = e1 > 0.f ? e1 : SLOPE * e1;
      e2 = e2 > 0.f ? e2 : SLOPE * e2;  e3 = e3 > 0.f ? e3 : SLOPE * e3;
      float w0 = __expf(e0), w1 = __expf(e1), w2 = __expf(e2), w3 = __expf(e3);
      acc0 += w0 * bflo(f0) + w1 * bflo(f1) + w2 * bflo(f2) + w3 * bflo(f3);
      acc1 += w0 * bfhi(f0) + w1 * bfhi(f1) + w2 * bfhi(f2) + w3 * bfhi(f3);
      den  += w0 + w1 + w2 + w3;
    }
    for (; i < num; i++) {
      int s = ssrc[beg + i];
      unsigned f = *(const unsigned*)(featb + (size_t)s * NCH + c0);
      float e = el[s * NH + hme] + erh;
      e = e > 0.f ? e : SLOPE * e;
      float wv = __expf(e);
      acc0 += wv * bflo(f); acc1 += wv * bfhi(f); den += wv;
    }
    float inv = den > 0.f ? 1.f / den : 0.f;
    float2 xv = *(const float2*)(x + (size_t)node * NCH + c0);
    float h0 = xv.x + acc0 * inv + gb0;
    float h1 = xv.y + acc1 * inv + gb1;
    *(float2*)(hbuf + (size_t)node * NCH + c0) = make_float2(h0, h1);
    s0 += h0; s1 += h1; q0 += h0 * h0; q1 += h1 * h1;
  }
  ps[w][c0] = s0; ps[w][c0 + 1] = s1;
  pq[w][c0] = q0; pq[w][c0 + 1] = q1;
  __syncthreads();
  if (tid < 128) {
    float ss = ps[0][tid] + ps[1][tid] + ps[2][tid] + ps[3][tid];
    float qq = pq[0][tid] + pq[1][tid] + pq[2][tid] + pq[3][tid];
    atomicAdd(&stats[tid * 16], ss);
    atomicAdd(&stats[2048 + tid * 16], qq);
  }
}

// ---------------- finalize mean/rstd ----------------
__global__ void stats_finalize(const float* __restrict__ stats, float* __restrict__ mu,
                               float* __restrict__ rs, int n, int so) {
  int c = threadIdx.x;
  if (c < 128) {
    float s = stats[so + c * 16], sq = stats[so + 2048 + c * 16];
    float m = s / (float)n;
    float v = sq / (float)n - m * m;
    mu[c] = m;
    rs[c] = rsqrtf(v + BN_EPS);
  }
}

// ---------------- fused BN1 + FFN v2: hid^T trick, rowA in registers ----------------
// 512 thr (8 waves), 128 rows/block, hidden chunked 4x128.
// fc1: D1 = hid^T = mfma(A=w1frag, B=rowAfrag)  [lane holds hid[row=lc][k=4*quad+reg]]
// repack via wave-private LDS scratch (no __syncthreads) into A-frags for fc2.
__global__ __launch_bounds__(512, 4) void ffn_mfma2(const float* __restrict__ hbuf,
                                                    const float* __restrict__ mu1, const float* __restrict__ rs1,
                                                    const float* __restrict__ g1, const float* __restrict__ be1,
                                                    const unsigned short* __restrict__ w1f,
                                                    const unsigned short* __restrict__ w2f,
                                                    const float* __restrict__ b1, const float* __restrict__ b2,
                                                    float* __restrict__ t, float* __restrict__ stats, int N) {
  __shared__ unsigned short w1t[16384];   // 32 KB (chunk: 8 ntiles x 4 kk frags)
  __shared__ unsigned short w2t[16384];   // 32 KB
  __shared__ unsigned short scr[8][512];  // 8 KB wave-private transpose scratch (1 frag)
  __shared__ float b1L[512];              // 2 KB
  __shared__ float psc[128], psh[128], b2L[128], csum[128], csq[128];  // 2.5 KB
  int tid = threadIdx.x;
  int lane = tid & 63, wid = tid >> 6;
  int quad = lane >> 4, lc = lane & 15;
  int r0 = blockIdx.x * 128;

  b1L[tid] = b1[tid];
  if (tid < 128) {
    float s = g1[tid] * rs1[tid];
    psc[tid] = s;
    psh[tid] = be1[tid] - s * mu1[tid];
    b2L[tid] = b2[tid];
    csum[tid] = 0.f; csq[tid] = 0.f;
  }

  // load this wave's 16 A-rows directly from global (BN1 applied after sync)
  int arow = r0 + wid * 16 + lc;
  float4 av[4][2];
  for (int kk = 0; kk < 4; kk++) {
    if (arow < N) {
      const float4* p = (const float4*)(hbuf + (size_t)arow * NCH + kk * 32 + quad * 8);
      av[kk][0] = p[0]; av[kk][1] = p[1];
    } else {
      av[kk][0] = make_float4(0.f, 0.f, 0.f, 0.f);
      av[kk][1] = make_float4(0.f, 0.f, 0.f, 0.f);
    }
  }
  __syncthreads();   // psc/psh ready

  short8 rowA[4];
  for (int kk = 0; kk < 4; kk++) {
    int c = kk * 32 + quad * 8;
    float4 s0 = *(float4*)&psc[c], s1 = *(float4*)&psc[c + 4];
    float4 h0 = *(float4*)&psh[c], h1 = *(float4*)&psh[c + 4];
    short8 r;
    r[0] = (short)f2bf(av[kk][0].x * s0.x + h0.x);
    r[1] = (short)f2bf(av[kk][0].y * s0.y + h0.y);
    r[2] = (short)f2bf(av[kk][0].z * s0.z + h0.z);
    r[3] = (short)f2bf(av[kk][0].w * s0.w + h0.w);
    r[4] = (short)f2bf(av[kk][1].x * s1.x + h1.x);
    r[5] = (short)f2bf(av[kk][1].y * s1.y + h1.y);
    r[6] = (short)f2bf(av[kk][1].z * s1.z + h1.z);
    r[7] = (short)f2bf(av[kk][1].w * s1.w + h1.w);
    rowA[kk] = r;
  }

  floatx4 acc2[8];
  for (int nt = 0; nt < 8; nt++) acc2[nt] = (floatx4)(0.f);

  for (int ch = 0; ch < 4; ch++) {
    __syncthreads();   // protect weight LDS from previous chunk's readers
    {
      const uint4* g1p = (const uint4*)(w1f + ch * 16384);
      const uint4* g2p = (const uint4*)(w2f + ch * 16384);
      uint4* l1 = (uint4*)w1t;
      uint4* l2 = (uint4*)w2t;
      for (int r = 0; r < 4; r++) {
        l1[tid + r * 512] = g1p[tid + r * 512];
        l2[tid + r * 512] = g2p[tid + r * 512];
      }
    }
    __syncthreads();

    for (int kk = 0; kk < 4; kk++) {
      // fc1: two hid^T tiles (hid cols 2kk*16 .. +31 of this chunk)
      floatx4 d0 = (floatx4)(0.f), d1 = (floatx4)(0.f);
      int t0 = 2 * kk, t1 = 2 * kk + 1;
      for (int kp = 0; kp < 4; kp++) {
        short8 a0 = *(const short8*)&w1t[(t0 * 4 + kp) * 512 + lane * 8];
        short8 a1 = *(const short8*)&w1t[(t1 * 4 + kp) * 512 + lane * 8];
        d0 = __builtin_amdgcn_mfma_f32_16x16x32_bf16(a0, rowA[kp], d0, 0, 0, 0);
        d1 = __builtin_amdgcn_mfma_f32_16x16x32_bf16(a1, rowA[kp], d1, 0, 0, 0);
      }
      // bias + relu + pack -> wave-private scratch (A-frag layout for fc2)
      {
        int bi0 = ch * 128 + t0 * 16 + 4 * quad;
        float4 bv0 = *(float4*)&b1L[bi0];
        float4 bv1 = *(float4*)&b1L[bi0 + 16];
        float v0, v1, v2, v3;
        unsigned lo, hi;
        int sidx;
        // t16 = 0
        v0 = fmaxf(d0[0] + bv0.x, 0.f); v1 = fmaxf(d0[1] + bv0.y, 0.f);
        v2 = fmaxf(d0[2] + bv0.z, 0.f); v3 = fmaxf(d0[3] + bv0.w, 0.f);
        lo = (unsigned)f2bf(v0) | ((unsigned)f2bf(v1) << 16);
        hi = (unsigned)f2bf(v2) | ((unsigned)f2bf(v3) << 16);
        sidx = ((quad >> 1) * 16 + lc) * 8 + 4 * (quad & 1);
        *(uint2*)&scr[wid][sidx] = make_uint2(lo, hi);
        // t16 = 1
        v0 = fmaxf(d1[0] + bv1.x, 0.f); v1 = fmaxf(d1[1] + bv1.y, 0.f);
        v2 = fmaxf(d1[2] + bv1.z, 0.f); v3 = fmaxf(d1[3] + bv1.w, 0.f);
        lo = (unsigned)f2bf(v0) | ((unsigned)f2bf(v1) << 16);
        hi = (unsigned)f2bf(v2) | ((unsigned)f2bf(v3) << 16);
        sidx = ((2 + (quad >> 1)) * 16 + lc) * 8 + 4 * (quad & 1);
        *(uint2*)&scr[wid][sidx] = make_uint2(lo, hi);
      }
      // fc2: consume this 32-k slice for all 8 output ntiles
      short8 a2 = *(const short8*)&scr[wid][lane * 8];
      for (int nt = 0; nt < 8; nt++) {
        short8 bfr = *(const short8*)&w2t[(nt * 4 + kk) * 512 + lane * 8];
        acc2[nt] = __builtin_amdgcn_mfma_f32_16x16x32_bf16(a2, bfr, acc2[nt], 0, 0, 0);
      }
    }
  }

  // epilogue: t = bf16(BN1(hbuf)) + y + b2, BN2 stats
  for (int nt = 0; nt < 8; nt++) {
    int col = nt * 16 + lc;
    float sc = psc[col], sh = psh[col], b2v = b2L[col];
    float s = 0.f, q = 0.f;
    for (int reg = 0; reg < 4; reg++) {
      int grow = r0 + wid * 16 + quad * 4 + reg;
      if (grow < N) {
        float hb = hbuf[(size_t)grow * NCH + col];
        float base = __uint_as_float(((unsigned)f2bf(sc * hb + sh)) << 16);
        float tv = base + acc2[nt][reg] + b2v;
        t[(size_t)grow * NCH + col] = tv;
        s += tv; q += tv * tv;
      }
    }
    s += __shfl_xor(s, 16); s += __shfl_xor(s, 32);
    q += __shfl_xor(q, 16); q += __shfl_xor(q, 32);
    if (quad == 0) { atomicAdd(&csum[col], s); atomicAdd(&csq[col], q); }
  }
  __syncthreads();
  if (tid < 128) {
    atomicAdd(&stats[4096 + tid * 16], csum[tid]);
    atomicAdd(&stats[6144 + tid * 16], csq[tid]);
  }
}

// ---------------- BN2 apply -> out ----------------
__global__ void bn2_apply(const float* __restrict__ t,
                          const float* __restrict__ g, const float* __restrict__ b,
                          const float* __restrict__ mu, const float* __restrict__ rs,
                          float* __restrict__ out, int total) {
  int i = blockIdx.x * blockDim.x + threadIdx.x;
  if (i >= total) return;
  int c = i & 127;
  out[i] = g[c] * (t[i] - mu[c]) * rs[c] + b[c];
}

extern "C" void kernel_launch(void* const* d_in, const int* in_sizes, int n_in,
                              void* d_out, int out_size, void* d_ws, size_t ws_size,
                              hipStream_t stream) {
  const float* x       = (const float*)d_in[0];
  const int*   src     = (const int*)d_in[1];
  const int*   dst     = (const int*)d_in[2];
  const float* W       = (const float*)d_in[3];
  const float* attn_l  = (const float*)d_in[4];
  const float* attn_r  = (const float*)d_in[5];
  const float* gatb    = (const float*)d_in[6];
  const float* gamma1  = (const float*)d_in[7];
  const float* beta1   = (const float*)d_in[8];
  const float* gamma2  = (const float*)d_in[9];
  const float* beta2   = (const float*)d_in[10];
  const float* W1      = (const float*)d_in[11];
  const float* b1      = (const float*)d_in[12];
  const float* W2      = (const float*)d_in[13];
  const float* b2      = (const float*)d_in[14];
  float* out = (float*)d_out;

  const int N = in_sizes[0] / NCH;   // 50000
  const int E = in_sizes[1];         // 800000
  const int nb = (N + 255) / 256;    // scan blocks

  float* hbuf  = (float*)d_ws;             // N*128 f32 (pre-BN1 h)
  float* t     = hbuf + (size_t)N * NCH;   // N*128 f32 (pre-BN2 t)
  float* el    = t + (size_t)N * NCH;      // N*8
  float* er    = el + (size_t)N * NH;      // N*8
  float* stats = er + (size_t)N * NH;      // 8192
  float* mus   = stats + 4 * 2048;         // mu1, rs1, mu2, rs2 (128 each)
  unsigned short* featb = (unsigned short*)(mus + 512);  // N*128 bf16
  unsigned short* WT    = featb + (size_t)N * NCH;       // 128*128 bf16
  unsigned short* w1f   = WT + NCH * NCH;                // 512*128 bf16 (frag order)
  unsigned short* w2f   = w1f + HID * NCH;               // 128*512 bf16 (frag order)
  int* cnt    = (int*)(w2f + HID * NCH);                 // N
  int* off    = cnt + N;                                 // N
  int* cursor = off + N;                                 // N
  int* bsum   = cursor + N;                              // 256
  int* ssrc   = bsum + 256;                              // E

  fill_zero4<<<(2048 + 255) / 256, 256, 0, stream>>>(stats, 2048);
  fill_zero4<<<(N / 4 + 255) / 256, 256, 0, stream>>>((float*)cnt, N / 4);

  prep_wbt<<<NCH * NCH / 256, 256, 0, stream>>>(W, WT);
  prep_w1f<<<HID * NCH / 256, 256, 0, stream>>>(W1, w1f);
  prep_w2f<<<HID * NCH / 256, 256, 0, stream>>>(W2, w2f);

  feat_mfma<<<(N + 63) / 64, 256, 0, stream>>>(x, WT, featb, N);
  compute_elr_b<<<(N * NH + 255) / 256, 256, 0, stream>>>(featb, attn_l, attn_r, el, er, N);

  edge_hist<<<(E + 255) / 256, 256, 0, stream>>>(dst, cnt, E);
  scan_part<<<nb, 256, 0, stream>>>(cnt, off, bsum, N);
  scan_top<<<1, 256, 0, stream>>>(bsum, nb);
  scan_add<<<nb, 256, 0, stream>>>(off, bsum, cursor, N);
  edge_scatter<<<(E + 255) / 256, 256, 0, stream>>>(src, dst, cursor, ssrc, E);

  gat_gather3<<<(N + 4 * NPW - 1) / (4 * NPW), 256, 0, stream>>>(ssrc, off, cnt, el, er, featb,
                                                                 x, gatb, hbuf, stats, N);
  stats_finalize<<<1, 128, 0, stream>>>(stats, mus, mus + 128, N, 0);

  ffn_mfma2<<<(N + 127) / 128, 512, 0, stream>>>(hbuf, mus, mus + 128, gamma1, beta1,
                                                 w1f, w2f, b1, b2, t, stats, N);
  stats_finalize<<<1, 128, 0, stream>>>(stats, mus + 256, mus + 384, N, 4096);

  bn2_apply<<<(N * NCH + 255) / 256, 256, 0, stream>>>(t, gamma2, beta2,
                                                       mus + 256, mus + 384, out, N * NCH);
}